// Round 8
// baseline (704.103 us; speedup 1.0000x reference)
//
#include <hip/hip_runtime.h>
#include <hip/hip_bf16.h>
#include <stdint.h>

// Problem constants
#define HW    65536          // 256*256
#define NB    4              // batch
#define CIN   192            // dim
#define OYC   288            // 192 q + 96 kv conv1x1 outputs
#define BSTR  200            // B-tile LDS row stride (bf16)
#define EPS2  264            // epilogue LDS row stride (bf16), 528 B = 16B-aligned

// ---- bf16 helpers (bf16 bits<<16 == fp32 bits) ----
__device__ __forceinline__ float bflo(unsigned u){ return __uint_as_float(u << 16); }
__device__ __forceinline__ float bfhi(unsigned u){ return __uint_as_float(u & 0xffff0000u); }
__device__ __forceinline__ float bf2f(__hip_bfloat16 v){ return __bfloat162float(v); }
__device__ __forceinline__ unsigned short f2bfbits(float f){
  __hip_bfloat16 h = __float2bfloat16(f); return *(unsigned short*)&h;
}

__device__ __forceinline__ void unpack8(uint4 u, float* f) {
  f[0]=bflo(u.x); f[1]=bfhi(u.x); f[2]=bflo(u.y); f[3]=bfhi(u.y);
  f[4]=bflo(u.z); f[5]=bfhi(u.z); f[6]=bflo(u.w); f[7]=bfhi(u.w);
}

union BF8 { uint4 u; __hip_bfloat16 h[8]; };

typedef __attribute__((ext_vector_type(8))) short short8;
typedef __attribute__((ext_vector_type(4))) float floatx4;

// ============================================================================
// K0: fold ln_w into W, emit A in MFMA-fragment order (bf16) + bias.
// ============================================================================
__global__ void k_prep(const float* __restrict__ qw, const float* __restrict__ kvw,
                       const float* __restrict__ lnw, const float* __restrict__ lnb,
                       __hip_bfloat16* __restrict__ AF, float* __restrict__ bias) {
  int blk = blockIdx.x, t = threadIdx.x;
  if (blk < 32) {
    for (int i = blk * 256 + t; i < OYC * CIN; i += 32 * 256) {
      int o = i / CIN, c = i % CIN;
      float w = (o < 192) ? qw[o * 192 + c] : kvw[(o - 192) * 192 + c];
      float val = w * lnw[c];
      int ot = o >> 4, lo = o & 15;
      int ks = c >> 5, cr = c & 31, q = cr >> 3, j = cr & 7;
      int dst = (((ot * 6 + ks) * 64) + q * 16 + lo) * 8 + j;
      AF[dst] = __float2bfloat16(val);
    }
  } else {
    for (int o = t; o < OYC; o += 256) {
      float s = 0.f;
      for (int c = 0; c < CIN; ++c)
        s += ((o < 192) ? qw[o * 192 + c] : kvw[(o - 192) * 192 + c]) * lnb[c];
      bias[o] = s;
    }
  }
}

// ============================================================================
// K1a: LayerNorm + fp32->bf16. Block = (b, row). Reads x strided (as before),
//      writes xT[b][r][px][192ch] = 96 KB fully-contiguous per block.
//      (de-fused from old k_conv1 so rocprof shows the load phase alone)
// ============================================================================
__global__ __launch_bounds__(512) void k_ln(const float* __restrict__ x,
                                            __hip_bfloat16* __restrict__ xT) {
  __shared__ __align__(16) __hip_bfloat16 Bl[256 * BSTR];
  __shared__ float part_s[8][256];
  __shared__ float part_q[8][256];
  __shared__ float murs_l[256][2];
  int bid = blockIdx.x;
  int b = bid >> 8, r = bid & 255;
  int tid = threadIdx.x;
  int w = tid >> 6, l = tid & 63;

  const float* xb = x + (size_t)(b * CIN + w * 24) * HW + r * 256 + l * 4;
  float xv[24][4];
  float s[4] = {0.f,0.f,0.f,0.f}, q2[4] = {0.f,0.f,0.f,0.f};
#pragma unroll
  for (int c = 0; c < 24; ++c) {
    float4 v4 = *(const float4*)(xb + (size_t)c * HW);
    xv[c][0] = v4.x; xv[c][1] = v4.y; xv[c][2] = v4.z; xv[c][3] = v4.w;
#pragma unroll
    for (int i = 0; i < 4; ++i) { s[i] += xv[c][i]; q2[i] += xv[c][i] * xv[c][i]; }
  }
  *(float4*)&part_s[w][l * 4] = make_float4(s[0], s[1], s[2], s[3]);
  *(float4*)&part_q[w][l * 4] = make_float4(q2[0], q2[1], q2[2], q2[3]);
  __syncthreads();
  if (tid < 256) {
    float s0 = 0.f, s1 = 0.f;
#pragma unroll
    for (int g = 0; g < 8; ++g) { s0 += part_s[g][tid]; s1 += part_q[g][tid]; }
    float m = s0 * (1.f / CIN);
    float var = s1 * (1.f / CIN) - m * m;
    murs_l[tid][0] = m;
    murs_l[tid][1] = rsqrtf(var + 1e-5f);
  }
  __syncthreads();
#pragma unroll
  for (int i = 0; i < 4; ++i) {
    int px = l * 4 + i;
    float mu = murs_l[px][0], rs = murs_l[px][1];
#pragma unroll
    for (int c = 0; c < 24; c += 2) {
      unsigned lo = f2bfbits((xv[c][i]     - mu) * rs);
      unsigned hi = f2bfbits((xv[c + 1][i] - mu) * rs);
      *(unsigned*)&Bl[px * BSTR + w * 24 + c] = lo | (hi << 16);
    }
  }
  __syncthreads();
  // flush Bl[px][192] -> xT contiguous 96 KB
  __hip_bfloat16* xTr = xT + (size_t)(b * 256 + r) * 49152;
  for (int i = tid; i < 6144; i += 512) {
    int px = i / 24, j = i % 24;
    *(uint4*)&xTr[px * 192 + j * 8] = *(const uint4*)&Bl[px * BSTR + j * 8];
  }
}

// ============================================================================
// K1b: conv1x1 GEMM: y[288][px] = AF * xT-row. Block = (b, row), 8 waves
//      (mh = o-half, nq = px-quarter). Stage xT (contiguous) -> Bl, MFMA,
//      LDS-transposed epilogue (+bias only; B already normalized).
// ============================================================================
__global__ __launch_bounds__(512) void k_mm(const __hip_bfloat16* __restrict__ xT,
                                            const __hip_bfloat16* __restrict__ AF,
                                            const float* __restrict__ bias,
                                            __hip_bfloat16* __restrict__ y) {
  __shared__ __align__(16) __hip_bfloat16 Bl[256 * BSTR];   // reused as EP
  __shared__ float biasl[OYC];
  int bid = blockIdx.x;
  int b = bid >> 8, r = bid & 255;
  int tid = threadIdx.x;

  for (int i = tid; i < OYC; i += 512) biasl[i] = bias[i];

  const __hip_bfloat16* xTr = xT + (size_t)(b * 256 + r) * 49152;
  for (int i = tid; i < 6144; i += 512) {
    int px = i / 24, j = i % 24;
    *(uint4*)&Bl[px * BSTR + j * 8] = *(const uint4*)&xTr[px * 192 + j * 8];
  }
  __syncthreads();

  int w = tid >> 6, lane = tid & 63;
  int mh = w >> 2, nq = w & 3;
  int li = lane & 15, qd = lane >> 4;

  floatx4 acc[9][4];
#pragma unroll
  for (int t = 0; t < 9; ++t)
#pragma unroll
    for (int nt = 0; nt < 4; ++nt) acc[t][nt] = (floatx4){0.f, 0.f, 0.f, 0.f};

  const __hip_bfloat16* abase = AF + ((size_t)(mh * 9) * 6 * 64 + lane) * 8;
  short8 a0[9], a1[9];
#pragma unroll
  for (int t = 0; t < 9; ++t) a0[t] = *(const short8*)(abase + (size_t)(t * 6) * 512);

#pragma unroll
  for (int ks = 0; ks < 6; ++ks) {
    short8 bf[4];
#pragma unroll
    for (int nt = 0; nt < 4; ++nt) {
      int px = nq * 64 + nt * 16 + li;
      bf[nt] = *(const short8*)&Bl[px * BSTR + ks * 32 + qd * 8];
    }
    if (ks < 5) {
#pragma unroll
      for (int t = 0; t < 9; ++t) {
        short8 v = *(const short8*)(abase + (size_t)(t * 6 + ks + 1) * 512);
        if (ks & 1) a0[t] = v; else a1[t] = v;
      }
    }
#pragma unroll
    for (int t = 0; t < 9; ++t) {
      short8 af = (ks & 1) ? a1[t] : a0[t];
#pragma unroll
      for (int nt = 0; nt < 4; ++nt)
        acc[t][nt] = __builtin_amdgcn_mfma_f32_16x16x32_bf16(af, bf[nt], acc[t][nt], 0, 0, 0);
    }
  }

  __hip_bfloat16* EP = Bl;
#pragma unroll
  for (int ph = 0; ph < 2; ++ph) {
    __syncthreads();   // Bl fragment reads done (ph0) / prev stores done (ph1)
    if (mh == ph) {
#pragma unroll
      for (int t = 0; t < 9; ++t)
#pragma unroll
        for (int nt = 0; nt < 4; ++nt) {
          int px = nq * 64 + nt * 16 + li;
#pragma unroll
          for (int rr = 0; rr < 4; ++rr) {
            int ol = t * 16 + qd * 4 + rr;
            EP[ol * EPS2 + px] = __float2bfloat16(acc[t][nt][rr] + biasl[ph * 144 + ol]);
          }
        }
    }
    __syncthreads();
    for (int i = tid; i < 144 * 32; i += 512) {
      int row = i >> 5, seg = i & 31;
      uint4 u = *(const uint4*)&EP[row * EPS2 + seg * 8];
      *(uint4*)&y[(size_t)(b * OYC + ph * 144 + row) * HW + r * 256 + seg * 8] = u;
    }
  }
}

// ============================================================================
// K2: depthwise 3x3 over kv channels. (unchanged)
// ============================================================================
__global__ __launch_bounds__(256) void k_dwkv(const __hip_bfloat16* __restrict__ y,
                                              const float* __restrict__ kvdw,
                                              __hip_bfloat16* __restrict__ kbuf,
                                              __hip_bfloat16* __restrict__ vbuf,
                                              float* __restrict__ kss) {
  __shared__ __align__(16) __hip_bfloat16 stage[18 * 256];
  int bid = blockIdx.x;
  int hb = bid & 15;
  int ck = (bid >> 4) % 96;
  int b  = bid / (16 * 96);
  int tid = threadIdx.x;
  int h0 = hb * 16;

  const __hip_bfloat16* yp = y + (size_t)(b * OYC + 192 + ck) * HW;
  for (int i = tid; i < 18 * 32; i += 256) {
    int ry = i >> 5, seg = i & 31;
    int hh = h0 - 1 + ry;
    uint4 u = make_uint4(0u, 0u, 0u, 0u);
    if ((unsigned)hh < 256u) u = *(const uint4*)(yp + hh * 256 + seg * 8);
    *(uint4*)&stage[ry * 256 + seg * 8] = u;
  }
  __syncthreads();

  float w[9];
#pragma unroll
  for (int i = 0; i < 9; ++i) w[i] = kvdw[ck * 9 + i];

  int cg = tid & 31, rg = tid >> 5;
  int c0 = cg * 8;
  bool isk = (ck < 48);
  __hip_bfloat16* ob = (isk ? kbuf : vbuf) + (size_t)(b * 48 + (ck % 48)) * HW;
  float ssq = 0.f;
#pragma unroll
  for (int rr = 0; rr < 2; ++rr) {
    int orow = rg * 2 + rr;
    float o[8];
#pragma unroll
    for (int j = 0; j < 8; ++j) o[j] = 0.f;
#pragma unroll
    for (int ry = 0; ry < 3; ++ry) {
      const __hip_bfloat16* rb = &stage[(orow + ry) * 256];
      float v[8];
      unpack8(*(const uint4*)&rb[c0], v);
      float vl = (c0 > 0)       ? bf2f(rb[c0 - 1]) : 0.f;
      float vr = (c0 + 8 < 256) ? bf2f(rb[c0 + 8]) : 0.f;
      float wl = w[ry * 3], wm = w[ry * 3 + 1], wr = w[ry * 3 + 2];
      o[0] = fmaf(wl, vl, fmaf(wm, v[0], fmaf(wr, v[1], o[0])));
#pragma unroll
      for (int j = 1; j < 7; ++j)
        o[j] = fmaf(wl, v[j-1], fmaf(wm, v[j], fmaf(wr, v[j+1], o[j])));
      o[7] = fmaf(wl, v[6], fmaf(wm, v[7], fmaf(wr, vr, o[7])));
    }
    BF8 t;
#pragma unroll
    for (int j = 0; j < 8; ++j) {
      t.h[j] = __float2bfloat16(o[j]);
      if (isk) { float fv = bf2f(t.h[j]); ssq += fv * fv; }
    }
    *(uint4*)(ob + (size_t)(h0 + orow) * 256 + c0) = t.u;
  }
  if (isk) {
#pragma unroll
    for (int off = 32; off > 0; off >>= 1) ssq += __shfl_down(ssq, off);
    __shared__ float ws4[4];
    if ((tid & 63) == 0) ws4[tid >> 6] = ssq;
    __syncthreads();
    if (tid == 0) atomicAdd(&kss[b * 48 + ck], ws4[0] + ws4[1] + ws4[2] + ws4[3]);
  }
}

// ============================================================================
// K3a: depthwise 3x3 over the 192 q channels -> qfull + sum(q^2). (unchanged)
// ============================================================================
__global__ __launch_bounds__(256) void k_dwq(const __hip_bfloat16* __restrict__ y,
                                             const float* __restrict__ qdw,
                                             __hip_bfloat16* __restrict__ qfull,
                                             float* __restrict__ qss) {
  __shared__ __align__(16) __hip_bfloat16 stage[18 * 256];
  int bid = blockIdx.x;
  int hb = bid & 15;
  int c  = (bid >> 4) % 192;
  int b  = bid / (16 * 192);
  int tid = threadIdx.x;
  int h0 = hb * 16;

  const __hip_bfloat16* yp = y + (size_t)(b * OYC + c) * HW;
  for (int i = tid; i < 18 * 32; i += 256) {
    int ry = i >> 5, seg = i & 31;
    int hh = h0 - 1 + ry;
    uint4 u = make_uint4(0u, 0u, 0u, 0u);
    if ((unsigned)hh < 256u) u = *(const uint4*)(yp + hh * 256 + seg * 8);
    *(uint4*)&stage[ry * 256 + seg * 8] = u;
  }
  __syncthreads();

  float w[9];
#pragma unroll
  for (int i = 0; i < 9; ++i) w[i] = qdw[c * 9 + i];

  int cg = tid & 31, rg = tid >> 5;
  int c0 = cg * 8;
  __hip_bfloat16* ob = qfull + (size_t)(b * CIN + c) * HW;
  float ssq = 0.f;
#pragma unroll
  for (int rr = 0; rr < 2; ++rr) {
    int orow = rg * 2 + rr;
    float o[8];
#pragma unroll
    for (int j = 0; j < 8; ++j) o[j] = 0.f;
#pragma unroll
    for (int ry = 0; ry < 3; ++ry) {
      const __hip_bfloat16* rb = &stage[(orow + ry) * 256];
      float v[8];
      unpack8(*(const uint4*)&rb[c0], v);
      float vl = (c0 > 0)       ? bf2f(rb[c0 - 1]) : 0.f;
      float vr = (c0 + 8 < 256) ? bf2f(rb[c0 + 8]) : 0.f;
      float wl = w[ry * 3], wm = w[ry * 3 + 1], wr = w[ry * 3 + 2];
      o[0] = fmaf(wl, vl, fmaf(wm, v[0], fmaf(wr, v[1], o[0])));
#pragma unroll
      for (int j = 1; j < 7; ++j)
        o[j] = fmaf(wl, v[j-1], fmaf(wm, v[j], fmaf(wr, v[j+1], o[j])));
      o[7] = fmaf(wl, v[6], fmaf(wm, v[7], fmaf(wr, vr, o[7])));
    }
    BF8 t;
#pragma unroll
    for (int j = 0; j < 8; ++j) {
      t.h[j] = __float2bfloat16(o[j]);
      float fv = bf2f(t.h[j]); ssq += fv * fv;
    }
    *(uint4*)(ob + (size_t)(h0 + orow) * 256 + c0) = t.u;
  }
#pragma unroll
  for (int off = 32; off > 0; off >>= 1) ssq += __shfl_down(ssq, off);
  __shared__ float ws4[4];
  if ((tid & 63) == 0) ws4[tid >> 6] = ssq;
  __syncthreads();
  if (tid == 0) atomicAdd(&qss[b * 192 + c], ws4[0] + ws4[1] + ws4[2] + ws4[3]);
}

// ============================================================================
// K3b: QK^T via bf16 MFMA, LDS-staged (fix 64B-granule fragment reads).
//      Block = (b,kvh,ck): 1024-px span, 4 sub-stages of 256 px. Coalesced
//      512B row reads into ql/kl; fragments from LDS; reduce as before.
// ============================================================================
__global__ __launch_bounds__(256) void k_qk(const __hip_bfloat16* __restrict__ qfull,
                                            const __hip_bfloat16* __restrict__ kbuf,
                                            float* __restrict__ attn) {
  __shared__ __align__(16) __hip_bfloat16 ql[96 * 264];
  __shared__ __align__(16) __hip_bfloat16 kl[24 * 264];
  __shared__ float red[96 * 33];
  int bid = blockIdx.x;
  int ck  = bid & 63;
  int kvh = (bid >> 6) & 1;
  int b   = bid >> 7;
  int tid = threadIdx.x;
  int wave = tid >> 6, lane = tid & 63;
  int li = lane & 15, qd = lane >> 4;

  for (int i = tid; i < 96 * 33; i += 256) red[i] = 0.f;

  const __hip_bfloat16* qp = qfull + (size_t)(b * CIN + kvh * 96) * HW + ck * 1024;
  const __hip_bfloat16* kp = kbuf  + (size_t)(b * 48 + kvh * 24) * HW + ck * 1024;

  floatx4 acc[6][2];
#pragma unroll
  for (int mt = 0; mt < 6; ++mt) {
    acc[mt][0] = (floatx4){0.f, 0.f, 0.f, 0.f};
    acc[mt][1] = (floatx4){0.f, 0.f, 0.f, 0.f};
  }

  int kr1 = 16 + li; if (kr1 > 23) kr1 = 23;   // clamp pad rows of N-tile 1
  for (int sc = 0; sc < 4; ++sc) {
    __syncthreads();   // prior sub-stage's fragment reads complete (and red zero on sc=0)
    for (int i = tid; i < 96 * 32; i += 256) {
      int row = i >> 5, seg = i & 31;
      *(uint4*)&ql[row * 264 + seg * 8] = *(const uint4*)(qp + (size_t)row * HW + sc * 256 + seg * 8);
    }
    for (int i = tid; i < 24 * 32; i += 256) {
      int row = i >> 5, seg = i & 31;
      *(uint4*)&kl[row * 264 + seg * 8] = *(const uint4*)(kp + (size_t)row * HW + sc * 256 + seg * 8);
    }
    __syncthreads();
#pragma unroll
    for (int ks = 0; ks < 2; ++ks) {
      int off = wave * 64 + ks * 32 + qd * 8;
      short8 bk0 = *(const short8*)&kl[li  * 264 + off];
      short8 bk1 = *(const short8*)&kl[kr1 * 264 + off];
#pragma unroll
      for (int mt = 0; mt < 6; ++mt) {
        short8 aq = *(const short8*)&ql[(mt * 16 + li) * 264 + off];
        acc[mt][0] = __builtin_amdgcn_mfma_f32_16x16x32_bf16(aq, bk0, acc[mt][0], 0, 0, 0);
        acc[mt][1] = __builtin_amdgcn_mfma_f32_16x16x32_bf16(aq, bk1, acc[mt][1], 0, 0, 0);
      }
    }
  }

  // D layout: col = lane&15 (n = k-ch), row = (lane>>4)*4 + r (m within tile)
#pragma unroll
  for (int mt = 0; mt < 6; ++mt) {
#pragma unroll
    for (int nt = 0; nt < 2; ++nt) {
      int n = nt * 16 + li;
      if (n < 24) {
#pragma unroll
        for (int r = 0; r < 4; ++r) {
          int m = mt * 16 + qd * 4 + r;
          atomicAdd(&red[m * 33 + n], acc[mt][nt][r]);
        }
      }
    }
  }
  __syncthreads();

  for (int i = tid; i < 96 * 24; i += 256) {
    int m = i / 24, d = i % 24;
    int head = kvh * 4 + m / 24, cp = m % 24;
    atomicAdd(&attn[(((b * 8 + head) * 24) + cp) * 24 + d], red[m * 33 + d]);
  }
}

// ============================================================================
// K4: l2norm scaling + temperature + softmax, fold proj_w. (unchanged)
// ============================================================================
__global__ void k_attn_final(const float* __restrict__ attn, const float* __restrict__ qss,
                             const float* __restrict__ kss, const float* __restrict__ temp,
                             const float* __restrict__ projw, float* __restrict__ Mt) {
  int b = blockIdx.x;
  int t = threadIdx.x;
  __shared__ float as_[96 * 25];
  float acc[48];
#pragma unroll
  for (int j = 0; j < 48; ++j) acc[j] = 0.f;
  for (int kvh = 0; kvh < 2; ++kvh) {
    __syncthreads();
    if (t < 96) {
      int row = kvh * 96 + t;
      int h = row / 24, cp = row % 24;
      float rq = 1.f / fmaxf(sqrtf(qss[b * 192 + row]), 1e-12f);
      float tp = temp[h];
      float lg[24]; float mx = -1e30f;
#pragma unroll
      for (int d = 0; d < 24; ++d) {
        float rk = 1.f / fmaxf(sqrtf(kss[b * 48 + kvh * 24 + d]), 1e-12f);
        float l = attn[(((b * 8 + h) * 24) + cp) * 24 + d] * rq * rk * tp;
        lg[d] = l; mx = fmaxf(mx, l);
      }
      float s = 0.f;
#pragma unroll
      for (int d = 0; d < 24; ++d) { lg[d] = __expf(lg[d] - mx); s += lg[d]; }
      float inv = 1.f / s;
#pragma unroll
      for (int d = 0; d < 24; ++d) as_[t * 25 + d] = lg[d] * inv;
    }
    __syncthreads();
    if (t < 192) {
      for (int cc = 0; cc < 96; ++cc) {
        float pw = projw[t * 192 + kvh * 96 + cc];
        const float* ar = &as_[cc * 25];
#pragma unroll
        for (int d = 0; d < 24; ++d) acc[kvh * 24 + d] = fmaf(pw, ar[d], acc[kvh * 24 + d]);
      }
    }
  }
  if (t < 192) {
#pragma unroll
    for (int j = 0; j < 48; ++j) Mt[((size_t)b * 48 + j) * 192 + t] = acc[j];
  }
}

// ============================================================================
// K5: out[b][o][n] = sum_j Mt[b][j][o] * v[b][j][n]. (unchanged)
// ============================================================================
__global__ __launch_bounds__(256) void k_out(const __hip_bfloat16* __restrict__ vbuf,
                                             const float* __restrict__ Mt,
                                             float* __restrict__ out) {
  __shared__ __align__(16) __hip_bfloat16 lv[48 * 256];
  int bid = blockIdx.x;
  int b  = bid >> 8;
  int n0 = (bid & 255) * 256;
  int tid = threadIdx.x;
  const __hip_bfloat16* vb = vbuf + (size_t)b * 48 * HW + n0;
  for (int i = tid; i < 48 * 32; i += 256) {
    int c = i >> 5, seg = i & 31;
    *(uint4*)&lv[c * 256 + seg * 8] = *(const uint4*)(vb + (size_t)c * HW + seg * 8);
  }
  __syncthreads();
  int wave = tid >> 6, ln = tid & 63;
  const float* mb = Mt + (size_t)b * 48 * 192;
  for (int ch = 0; ch < 2; ++ch) {
    int o0 = wave * 48 + ch * 24;
    float acc[24][4];
#pragma unroll
    for (int j = 0; j < 24; ++j)
#pragma unroll
      for (int e = 0; e < 4; ++e) acc[j][e] = 0.f;
    for (int c = 0; c < 48; ++c) {
      float xv[4];
      uint2 u = *(const uint2*)&lv[c * 256 + ln * 4];
      xv[0] = bflo(u.x); xv[1] = bfhi(u.x); xv[2] = bflo(u.y); xv[3] = bfhi(u.y);
      const float* mrow = mb + c * 192 + o0;
      float4 m[6];
#pragma unroll
      for (int gg = 0; gg < 6; ++gg) m[gg] = *(const float4*)(mrow + gg * 4);
      const float* mf = (const float*)&m[0];
#pragma unroll
      for (int j = 0; j < 24; ++j) {
        float mv = mf[j];
#pragma unroll
        for (int e = 0; e < 4; ++e) acc[j][e] = fmaf(mv, xv[e], acc[j][e]);
      }
    }
#pragma unroll
    for (int j = 0; j < 24; ++j) {
      float4 st = make_float4(acc[j][0], acc[j][1], acc[j][2], acc[j][3]);
      *(float4*)&out[(size_t)(b * 192 + o0 + j) * HW + n0 + ln * 4] = st;
    }
  }
}

// ============================================================================
// ws layout (float offsets):
//  0        qss   [4*192]      = 768
//  768      kss   [4*48]       = 192
//  960      attn  [4*8*24*24]  = 18432
//  19392    Mt    [4*48*192]   = 36864
//  56256    bias  [288]
//  56832    AF  bf16 [288*192]
//  111872   y   bf16 [4*288*HW]
//  37860608 kbuf bf16 [4*48*HW]
//  44152064 vbuf bf16 [4*48*HW]
// d_out scratch (201.3 MB): [0,100.66MB) qfull bf16; [100.66MB,201.3MB) xT bf16.
// Order: k_ln writes xT -> k_mm reads xT -> ... -> k_dwq writes qfull ->
// k_qk reads qfull -> k_out overwrites all of d_out. Stream-serial => safe.
// ============================================================================
extern "C" void kernel_launch(void* const* d_in, const int* in_sizes, int n_in,
                              void* d_out, int out_size, void* d_ws, size_t ws_size,
                              hipStream_t stream) {
  const float* x     = (const float*)d_in[0];
  const float* ln_w  = (const float*)d_in[1];
  const float* ln_b  = (const float*)d_in[2];
  const float* q_w   = (const float*)d_in[3];
  const float* q_dw  = (const float*)d_in[4];
  const float* kv_w  = (const float*)d_in[5];
  const float* kv_dw = (const float*)d_in[6];
  const float* projw = (const float*)d_in[7];
  const float* temp  = (const float*)d_in[8];
  float* out = (float*)d_out;
  float* wsf = (float*)d_ws;

  float* qss  = wsf;
  float* kss  = wsf + 768;
  float* attn = wsf + 960;
  float* Mt   = wsf + 19392;
  float* bias = wsf + 56256;
  __hip_bfloat16* AF = (__hip_bfloat16*)(wsf + 56832);
  __hip_bfloat16* y    = (__hip_bfloat16*)(wsf + 111872);
  __hip_bfloat16* kbuf = (__hip_bfloat16*)(wsf + 37860608);
  __hip_bfloat16* vbuf = (__hip_bfloat16*)(wsf + 44152064);
  __hip_bfloat16* qfull = (__hip_bfloat16*)d_out;                       // lower half of d_out
  __hip_bfloat16* xT    = (__hip_bfloat16*)((char*)d_out + 100663296);  // upper half of d_out

  hipMemsetAsync(wsf, 0, 19392 * sizeof(float), stream);  // qss+kss+attn accumulators
  hipLaunchKernelGGL(k_prep, dim3(33), dim3(256), 0, stream, q_w, kv_w, ln_w, ln_b, AF, bias);
  hipLaunchKernelGGL(k_ln,   dim3(NB * 256), dim3(512), 0, stream, x, xT);
  hipLaunchKernelGGL(k_mm,   dim3(NB * 256), dim3(512), 0, stream, xT, AF, bias, y);
  hipLaunchKernelGGL(k_dwkv, dim3(NB * 96 * 16), dim3(256), 0, stream, y, kv_dw, kbuf, vbuf, kss);
  hipLaunchKernelGGL(k_dwq,  dim3(NB * 192 * 16), dim3(256), 0, stream, y, q_dw, qfull, qss);
  hipLaunchKernelGGL(k_qk,   dim3(NB * 2 * 64), dim3(256), 0, stream, qfull, kbuf, attn);
  hipLaunchKernelGGL(k_attn_final, dim3(NB), dim3(256), 0, stream, attn, qss, kss, temp, projw, Mt);
  hipLaunchKernelGGL(k_out,  dim3(NB * 256), dim3(256), 0, stream, vbuf, Mt, out);
}

// Round 9
// 607.618 us; speedup vs baseline: 1.1588x; 1.1588x over previous
//
#include <hip/hip_runtime.h>
#include <hip/hip_bf16.h>
#include <stdint.h>

// Problem constants
#define HW    65536          // 256*256
#define NB    4              // batch
#define CIN   192            // dim
#define OYC   288            // 192 q + 96 kv conv1x1 outputs
#define BSTR  200            // B-tile LDS row stride (bf16)
#define EPS2  264            // k_conv1r epilogue LDS row stride (bf16)

// ---- bf16 helpers (bf16 bits<<16 == fp32 bits) ----
__device__ __forceinline__ float bflo(unsigned u){ return __uint_as_float(u << 16); }
__device__ __forceinline__ float bfhi(unsigned u){ return __uint_as_float(u & 0xffff0000u); }
__device__ __forceinline__ float bf2f(__hip_bfloat16 v){ return __bfloat162float(v); }
__device__ __forceinline__ unsigned short f2bfbits(float f){
  __hip_bfloat16 h = __float2bfloat16(f); return *(unsigned short*)&h;
}

__device__ __forceinline__ void unpack8(uint4 u, float* f) {
  f[0]=bflo(u.x); f[1]=bfhi(u.x); f[2]=bflo(u.y); f[3]=bfhi(u.y);
  f[4]=bflo(u.z); f[5]=bfhi(u.z); f[6]=bflo(u.w); f[7]=bfhi(u.w);
}

union BF8 { uint4 u; __hip_bfloat16 h[8]; };

typedef __attribute__((ext_vector_type(8))) short short8;
typedef __attribute__((ext_vector_type(4))) float floatx4;

// ============================================================================
// K0: fold ln_w into W, emit A in MFMA-fragment order (bf16) + bias + Ssum.
// Ssum[o] = sum_c bf16(W[o][c]*lnw[c])  (must match AF rounding exactly)
// ============================================================================
__global__ void k_prep(const float* __restrict__ qw, const float* __restrict__ kvw,
                       const float* __restrict__ lnw, const float* __restrict__ lnb,
                       __hip_bfloat16* __restrict__ AF, float* __restrict__ bias,
                       float* __restrict__ Ssum) {
  int blk = blockIdx.x, t = threadIdx.x;
  if (blk < 32) {
    for (int i = blk * 256 + t; i < OYC * CIN; i += 32 * 256) {
      int o = i / CIN, c = i % CIN;
      float w = (o < 192) ? qw[o * 192 + c] : kvw[(o - 192) * 192 + c];
      float val = w * lnw[c];
      int ot = o >> 4, lo = o & 15;
      int ks = c >> 5, cr = c & 31, q = cr >> 3, j = cr & 7;
      int dst = (((ot * 6 + ks) * 64) + q * 16 + lo) * 8 + j;
      AF[dst] = __float2bfloat16(val);
    }
  } else {
    for (int o = t; o < OYC; o += 256) {
      float s = 0.f, s2 = 0.f;
      for (int c = 0; c < CIN; ++c) {
        float w = (o < 192) ? qw[o * 192 + c] : kvw[(o - 192) * 192 + c];
        s += w * lnb[c];
        s2 += bf2f(__float2bfloat16(w * lnw[c]));
      }
      bias[o] = s;
      Ssum[o] = s2;
    }
  }
}

// ============================================================================
// K1: fused LayerNorm + conv1x1, one FULL ROW (256 px) per block (round-3
//     version, measured 142 us). LN folded into epilogue:
//     y = rs*(G - mu*S) + bias; GEMM runs on raw bf16 x.
// ============================================================================
__global__ __launch_bounds__(512, 2) void k_conv1r(const float* __restrict__ x,
                                                   const __hip_bfloat16* __restrict__ AF,
                                                   const float* __restrict__ bias,
                                                   const float* __restrict__ Ssum,
                                                   __hip_bfloat16* __restrict__ y) {
  __shared__ __align__(16) __hip_bfloat16 Bl[256 * BSTR];   // reused as EP
  __shared__ float part_s[8][256];
  __shared__ float part_q[8][256];
  __shared__ float murs[256][2];
  __shared__ float biasl[OYC];
  __shared__ float Sl[OYC];

  int bid = blockIdx.x;
  int b = bid >> 8;
  int r = bid & 255;           // image row
  int tid = threadIdx.x;
  int w = tid >> 6, l = tid & 63;

  for (int i = tid; i < OYC; i += 512) { biasl[i] = bias[i]; Sl[i] = Ssum[i]; }

  // phase 1: wave w loads channels [w*24,+24) for 256 px (4 px/lane, float4)
  {
    const float* xb = x + (size_t)(b * CIN + w * 24) * HW + r * 256 + l * 4;
    float s[4] = {0.f, 0.f, 0.f, 0.f}, q2[4] = {0.f, 0.f, 0.f, 0.f};
    unsigned pk[4][12];
#pragma unroll
    for (int c = 0; c < 24; ++c) {
      float4 v4 = *(const float4*)(xb + (size_t)c * HW);
      float vv[4] = {v4.x, v4.y, v4.z, v4.w};
#pragma unroll
      for (int i = 0; i < 4; ++i) {
        s[i] += vv[i]; q2[i] += vv[i] * vv[i];
        unsigned bits = f2bfbits(vv[i]);
        if ((c & 1) == 0) pk[i][c >> 1] = bits;
        else              pk[i][c >> 1] |= bits << 16;
      }
    }
#pragma unroll
    for (int i = 0; i < 4; ++i) {
      int px = l * 4 + i;
#pragma unroll
      for (int j = 0; j < 3; ++j) {
        uint4 u = make_uint4(pk[i][j*4], pk[i][j*4+1], pk[i][j*4+2], pk[i][j*4+3]);
        *(uint4*)&Bl[px * BSTR + w * 24 + j * 8] = u;
      }
    }
    *(float4*)&part_s[w][l * 4] = make_float4(s[0], s[1], s[2], s[3]);
    *(float4*)&part_q[w][l * 4] = make_float4(q2[0], q2[1], q2[2], q2[3]);
  }
  __syncthreads();

  // phase 2: MFMA. wave: mh = o-half (9 tiles), nq = px-quarter (4 N-tiles).
  int lane = tid & 63;
  int mh = w >> 2, nq = w & 3;
  int li = lane & 15, qd = lane >> 4;

  floatx4 acc[9][4];
#pragma unroll
  for (int t = 0; t < 9; ++t)
#pragma unroll
    for (int nt = 0; nt < 4; ++nt) acc[t][nt] = (floatx4){0.f, 0.f, 0.f, 0.f};

  const __hip_bfloat16* abase = AF + ((size_t)(mh * 9) * 6 * 64 + lane) * 8;
  short8 a0[9], a1[9];
#pragma unroll
  for (int t = 0; t < 9; ++t) a0[t] = *(const short8*)(abase + (size_t)(t * 6) * 512);

#pragma unroll
  for (int ks = 0; ks < 6; ++ks) {
    short8 bf[4];
#pragma unroll
    for (int nt = 0; nt < 4; ++nt) {
      int px = nq * 64 + nt * 16 + li;
      bf[nt] = *(const short8*)&Bl[px * BSTR + ks * 32 + qd * 8];
    }
    if (ks < 5) {
#pragma unroll
      for (int t = 0; t < 9; ++t) {
        short8 v = *(const short8*)(abase + (size_t)(t * 6 + ks + 1) * 512);
        if (ks & 1) a0[t] = v; else a1[t] = v;
      }
    }
#pragma unroll
    for (int t = 0; t < 9; ++t) {
      short8 af = (ks & 1) ? a1[t] : a0[t];
#pragma unroll
      for (int nt = 0; nt < 4; ++nt)
        acc[t][nt] = __builtin_amdgcn_mfma_f32_16x16x32_bf16(af, bf[nt], acc[t][nt], 0, 0, 0);
    }
  }

  // LN stats reduce (overlaps other waves' MFMA tails)
  if (tid < 256) {
    float s0 = 0.f, s1 = 0.f;
#pragma unroll
    for (int g = 0; g < 8; ++g) { s0 += part_s[g][tid]; s1 += part_q[g][tid]; }
    float m = s0 * (1.f / CIN);
    float var = s1 * (1.f / CIN) - m * m;
    murs[tid][0] = m;
    murs[tid][1] = rsqrtf(var + 1e-5f);
  }

  // epilogue: 2 phases of 144 o-rows; EP[o_local][px] then 512 B stores
  __hip_bfloat16* EP = Bl;
#pragma unroll
  for (int ph = 0; ph < 2; ++ph) {
    __syncthreads();
    if (mh == ph) {
#pragma unroll
      for (int t = 0; t < 9; ++t)
#pragma unroll
        for (int nt = 0; nt < 4; ++nt) {
          int px = nq * 64 + nt * 16 + li;
          float mu = murs[px][0], rs = murs[px][1];
#pragma unroll
          for (int rr = 0; rr < 4; ++rr) {
            int ol = t * 16 + qd * 4 + rr;
            float val = rs * (acc[t][nt][rr] - mu * Sl[ph * 144 + ol]) + biasl[ph * 144 + ol];
            EP[ol * EPS2 + px] = __float2bfloat16(val);
          }
        }
    }
    __syncthreads();
    for (int i = tid; i < 144 * 32; i += 512) {
      int row = i >> 5, seg = i & 31;
      uint4 u = *(const uint4*)&EP[row * EPS2 + seg * 8];
      *(uint4*)&y[(size_t)(b * OYC + ph * 144 + row) * HW + r * 256 + seg * 8] = u;
    }
  }
}

// ============================================================================
// K2: depthwise 3x3 over kv channels. (unchanged)
// ============================================================================
__global__ __launch_bounds__(256) void k_dwkv(const __hip_bfloat16* __restrict__ y,
                                              const float* __restrict__ kvdw,
                                              __hip_bfloat16* __restrict__ kbuf,
                                              __hip_bfloat16* __restrict__ vbuf,
                                              float* __restrict__ kss) {
  __shared__ __align__(16) __hip_bfloat16 stage[18 * 256];
  int bid = blockIdx.x;
  int hb = bid & 15;
  int ck = (bid >> 4) % 96;
  int b  = bid / (16 * 96);
  int tid = threadIdx.x;
  int h0 = hb * 16;

  const __hip_bfloat16* yp = y + (size_t)(b * OYC + 192 + ck) * HW;
  for (int i = tid; i < 18 * 32; i += 256) {
    int ry = i >> 5, seg = i & 31;
    int hh = h0 - 1 + ry;
    uint4 u = make_uint4(0u, 0u, 0u, 0u);
    if ((unsigned)hh < 256u) u = *(const uint4*)(yp + hh * 256 + seg * 8);
    *(uint4*)&stage[ry * 256 + seg * 8] = u;
  }
  __syncthreads();

  float w[9];
#pragma unroll
  for (int i = 0; i < 9; ++i) w[i] = kvdw[ck * 9 + i];

  int cg = tid & 31, rg = tid >> 5;
  int c0 = cg * 8;
  bool isk = (ck < 48);
  __hip_bfloat16* ob = (isk ? kbuf : vbuf) + (size_t)(b * 48 + (ck % 48)) * HW;
  float ssq = 0.f;
#pragma unroll
  for (int rr = 0; rr < 2; ++rr) {
    int orow = rg * 2 + rr;
    float o[8];
#pragma unroll
    for (int j = 0; j < 8; ++j) o[j] = 0.f;
#pragma unroll
    for (int ry = 0; ry < 3; ++ry) {
      const __hip_bfloat16* rb = &stage[(orow + ry) * 256];
      float v[8];
      unpack8(*(const uint4*)&rb[c0], v);
      float vl = (c0 > 0)       ? bf2f(rb[c0 - 1]) : 0.f;
      float vr = (c0 + 8 < 256) ? bf2f(rb[c0 + 8]) : 0.f;
      float wl = w[ry * 3], wm = w[ry * 3 + 1], wr = w[ry * 3 + 2];
      o[0] = fmaf(wl, vl, fmaf(wm, v[0], fmaf(wr, v[1], o[0])));
#pragma unroll
      for (int j = 1; j < 7; ++j)
        o[j] = fmaf(wl, v[j-1], fmaf(wm, v[j], fmaf(wr, v[j+1], o[j])));
      o[7] = fmaf(wl, v[6], fmaf(wm, v[7], fmaf(wr, vr, o[7])));
    }
    BF8 t;
#pragma unroll
    for (int j = 0; j < 8; ++j) {
      t.h[j] = __float2bfloat16(o[j]);
      if (isk) { float fv = bf2f(t.h[j]); ssq += fv * fv; }
    }
    *(uint4*)(ob + (size_t)(h0 + orow) * 256 + c0) = t.u;
  }
  if (isk) {
#pragma unroll
    for (int off = 32; off > 0; off >>= 1) ssq += __shfl_down(ssq, off);
    __shared__ float ws4[4];
    if ((tid & 63) == 0) ws4[tid >> 6] = ssq;
    __syncthreads();
    if (tid == 0) atomicAdd(&kss[b * 48 + ck], ws4[0] + ws4[1] + ws4[2] + ws4[3]);
  }
}

// ============================================================================
// K3a: depthwise 3x3 over the 192 q channels -> qfull + sum(q^2). (unchanged)
// ============================================================================
__global__ __launch_bounds__(256) void k_dwq(const __hip_bfloat16* __restrict__ y,
                                             const float* __restrict__ qdw,
                                             __hip_bfloat16* __restrict__ qfull,
                                             float* __restrict__ qss) {
  __shared__ __align__(16) __hip_bfloat16 stage[18 * 256];
  int bid = blockIdx.x;
  int hb = bid & 15;
  int c  = (bid >> 4) % 192;
  int b  = bid / (16 * 192);
  int tid = threadIdx.x;
  int h0 = hb * 16;

  const __hip_bfloat16* yp = y + (size_t)(b * OYC + c) * HW;
  for (int i = tid; i < 18 * 32; i += 256) {
    int ry = i >> 5, seg = i & 31;
    int hh = h0 - 1 + ry;
    uint4 u = make_uint4(0u, 0u, 0u, 0u);
    if ((unsigned)hh < 256u) u = *(const uint4*)(yp + hh * 256 + seg * 8);
    *(uint4*)&stage[ry * 256 + seg * 8] = u;
  }
  __syncthreads();

  float w[9];
#pragma unroll
  for (int i = 0; i < 9; ++i) w[i] = qdw[c * 9 + i];

  int cg = tid & 31, rg = tid >> 5;
  int c0 = cg * 8;
  __hip_bfloat16* ob = qfull + (size_t)(b * CIN + c) * HW;
  float ssq = 0.f;
#pragma unroll
  for (int rr = 0; rr < 2; ++rr) {
    int orow = rg * 2 + rr;
    float o[8];
#pragma unroll
    for (int j = 0; j < 8; ++j) o[j] = 0.f;
#pragma unroll
    for (int ry = 0; ry < 3; ++ry) {
      const __hip_bfloat16* rb = &stage[(orow + ry) * 256];
      float v[8];
      unpack8(*(const uint4*)&rb[c0], v);
      float vl = (c0 > 0)       ? bf2f(rb[c0 - 1]) : 0.f;
      float vr = (c0 + 8 < 256) ? bf2f(rb[c0 + 8]) : 0.f;
      float wl = w[ry * 3], wm = w[ry * 3 + 1], wr = w[ry * 3 + 2];
      o[0] = fmaf(wl, vl, fmaf(wm, v[0], fmaf(wr, v[1], o[0])));
#pragma unroll
      for (int j = 1; j < 7; ++j)
        o[j] = fmaf(wl, v[j-1], fmaf(wm, v[j], fmaf(wr, v[j+1], o[j])));
      o[7] = fmaf(wl, v[6], fmaf(wm, v[7], fmaf(wr, vr, o[7])));
    }
    BF8 t;
#pragma unroll
    for (int j = 0; j < 8; ++j) {
      t.h[j] = __float2bfloat16(o[j]);
      float fv = bf2f(t.h[j]); ssq += fv * fv;
    }
    *(uint4*)(ob + (size_t)(h0 + orow) * 256 + c0) = t.u;
  }
#pragma unroll
  for (int off = 32; off > 0; off >>= 1) ssq += __shfl_down(ssq, off);
  __shared__ float ws4[4];
  if ((tid & 63) == 0) ws4[tid >> 6] = ssq;
  __syncthreads();
  if (tid == 0) atomicAdd(&qss[b * 192 + c], ws4[0] + ws4[1] + ws4[2] + ws4[3]);
}

// ============================================================================
// K3b: QK^T via bf16 MFMA, LDS-staged. (unchanged, in 704-us measured build)
// ============================================================================
__global__ __launch_bounds__(256) void k_qk(const __hip_bfloat16* __restrict__ qfull,
                                            const __hip_bfloat16* __restrict__ kbuf,
                                            float* __restrict__ attn) {
  __shared__ __align__(16) __hip_bfloat16 ql[96 * 264];
  __shared__ __align__(16) __hip_bfloat16 kl[24 * 264];
  __shared__ float red[96 * 33];
  int bid = blockIdx.x;
  int ck  = bid & 63;
  int kvh = (bid >> 6) & 1;
  int b   = bid >> 7;
  int tid = threadIdx.x;
  int wave = tid >> 6, lane = tid & 63;
  int li = lane & 15, qd = lane >> 4;

  for (int i = tid; i < 96 * 33; i += 256) red[i] = 0.f;

  const __hip_bfloat16* qp = qfull + (size_t)(b * CIN + kvh * 96) * HW + ck * 1024;
  const __hip_bfloat16* kp = kbuf  + (size_t)(b * 48 + kvh * 24) * HW + ck * 1024;

  floatx4 acc[6][2];
#pragma unroll
  for (int mt = 0; mt < 6; ++mt) {
    acc[mt][0] = (floatx4){0.f, 0.f, 0.f, 0.f};
    acc[mt][1] = (floatx4){0.f, 0.f, 0.f, 0.f};
  }

  int kr1 = 16 + li; if (kr1 > 23) kr1 = 23;
  for (int sc = 0; sc < 4; ++sc) {
    __syncthreads();
    for (int i = tid; i < 96 * 32; i += 256) {
      int row = i >> 5, seg = i & 31;
      *(uint4*)&ql[row * 264 + seg * 8] = *(const uint4*)(qp + (size_t)row * HW + sc * 256 + seg * 8);
    }
    for (int i = tid; i < 24 * 32; i += 256) {
      int row = i >> 5, seg = i & 31;
      *(uint4*)&kl[row * 264 + seg * 8] = *(const uint4*)(kp + (size_t)row * HW + sc * 256 + seg * 8);
    }
    __syncthreads();
#pragma unroll
    for (int ks = 0; ks < 2; ++ks) {
      int off = wave * 64 + ks * 32 + qd * 8;
      short8 bk0 = *(const short8*)&kl[li  * 264 + off];
      short8 bk1 = *(const short8*)&kl[kr1 * 264 + off];
#pragma unroll
      for (int mt = 0; mt < 6; ++mt) {
        short8 aq = *(const short8*)&ql[(mt * 16 + li) * 264 + off];
        acc[mt][0] = __builtin_amdgcn_mfma_f32_16x16x32_bf16(aq, bk0, acc[mt][0], 0, 0, 0);
        acc[mt][1] = __builtin_amdgcn_mfma_f32_16x16x32_bf16(aq, bk1, acc[mt][1], 0, 0, 0);
      }
    }
  }

#pragma unroll
  for (int mt = 0; mt < 6; ++mt) {
#pragma unroll
    for (int nt = 0; nt < 2; ++nt) {
      int n = nt * 16 + li;
      if (n < 24) {
#pragma unroll
        for (int r = 0; r < 4; ++r) {
          int m = mt * 16 + qd * 4 + r;
          atomicAdd(&red[m * 33 + n], acc[mt][nt][r]);
        }
      }
    }
  }
  __syncthreads();

  for (int i = tid; i < 96 * 24; i += 256) {
    int m = i / 24, d = i % 24;
    int head = kvh * 4 + m / 24, cp = m % 24;
    atomicAdd(&attn[(((b * 8 + head) * 24) + cp) * 24 + d], red[m * 33 + d]);
  }
}

// ============================================================================
// K4: l2norm scaling + temperature + softmax, fold proj_w.
//     NEW: emit M = [hi(Mt) | lo(Mt)] (double-bf16) in MFMA A-fragment order:
//     AB[b][((mt*3+s)*64 + lane)*8 + jj], element (o,kk):
//       mt=o>>4, s=kk>>5, lane=(o&15)+16*((kk&31)>>3), jj=kk&7
//       kk<48: hi_j (j=kk);  kk>=48: lo_j (j=kk-48)
// ============================================================================
__global__ void k_attn_final(const float* __restrict__ attn, const float* __restrict__ qss,
                             const float* __restrict__ kss, const float* __restrict__ temp,
                             const float* __restrict__ projw, __hip_bfloat16* __restrict__ AB) {
  int b = blockIdx.x;
  int t = threadIdx.x;
  __shared__ float as_[96 * 25];
  float acc[48];
#pragma unroll
  for (int j = 0; j < 48; ++j) acc[j] = 0.f;
  for (int kvh = 0; kvh < 2; ++kvh) {
    __syncthreads();
    if (t < 96) {
      int row = kvh * 96 + t;
      int h = row / 24, cp = row % 24;
      float rq = 1.f / fmaxf(sqrtf(qss[b * 192 + row]), 1e-12f);
      float tp = temp[h];
      float lg[24]; float mx = -1e30f;
#pragma unroll
      for (int d = 0; d < 24; ++d) {
        float rk = 1.f / fmaxf(sqrtf(kss[b * 48 + kvh * 24 + d]), 1e-12f);
        float l = attn[(((b * 8 + h) * 24) + cp) * 24 + d] * rq * rk * tp;
        lg[d] = l; mx = fmaxf(mx, l);
      }
      float s = 0.f;
#pragma unroll
      for (int d = 0; d < 24; ++d) { lg[d] = __expf(lg[d] - mx); s += lg[d]; }
      float inv = 1.f / s;
#pragma unroll
      for (int d = 0; d < 24; ++d) as_[t * 25 + d] = lg[d] * inv;
    }
    __syncthreads();
    if (t < 192) {
      for (int cc = 0; cc < 96; ++cc) {
        float pw = projw[t * 192 + kvh * 96 + cc];
        const float* ar = &as_[cc * 25];
#pragma unroll
        for (int d = 0; d < 24; ++d) acc[kvh * 24 + d] = fmaf(pw, ar[d], acc[kvh * 24 + d]);
      }
    }
  }
  if (t < 192) {
    __hip_bfloat16* ABb = AB + (size_t)b * 18432;
    int mt = t >> 4, lb = t & 15;
#pragma unroll
    for (int g = 0; g < 12; ++g) {
      int kk0 = g * 8;
      int s = kk0 >> 5;
      int lane = lb + 16 * ((kk0 & 31) >> 3);
      BF8 u;
#pragma unroll
      for (int jj = 0; jj < 8; ++jj) {
        int kk = kk0 + jj;
        if (kk < 48) {
          u.h[jj] = __float2bfloat16(acc[kk]);
        } else {
          int j = kk - 48;
          float hv = bf2f(__float2bfloat16(acc[j]));
          u.h[jj] = __float2bfloat16(acc[j] - hv);
        }
      }
      *(uint4*)(ABb + (size_t)((mt * 3 + s) * 64 + lane) * 8) = u.u;
    }
  }
}

// ============================================================================
// K5 (rewritten): out = M(192x96) @ B(96xN) via bf16 MFMA, fp32 accumulate.
//   Block = (b, 256-px span), 512 threads / 8 waves (mg = M-group of 3 tiles,
//   nh = N-half of 128 px). v staged coalesced -> vl, transposed -> vT[px][j],
//   A-frags streamed from L2 (AB). 4-phase LDS fp32 epilogue, 1KB row stores.
// ============================================================================
__global__ __launch_bounds__(512) void k_out(const __hip_bfloat16* __restrict__ vbuf,
                                             const __hip_bfloat16* __restrict__ AB,
                                             float* __restrict__ out) {
  __shared__ __align__(16) __hip_bfloat16 vT[256 * 56];   // [px][j] (j-contig)
  __shared__ __align__(16) float EPu[48 * 260];           // union: vl (staging) / EP (epilogue)
  __hip_bfloat16* vl = (__hip_bfloat16*)EPu;              // [48][264]

  int bid = blockIdx.x;
  int b  = bid >> 8;
  int n0 = (bid & 255) * 256;
  int tid = threadIdx.x;

  // stage 1: global -> vl (coalesced 512B rows)
  const __hip_bfloat16* vb = vbuf + (size_t)b * 48 * HW + n0;
  for (int i = tid; i < 48 * 32; i += 512) {
    int j = i >> 5, seg = i & 31;
    *(uint4*)&vl[j * 264 + seg * 8] = *(const uint4*)(vb + (size_t)j * HW + seg * 8);
  }
  __syncthreads();
  // stage 2: vl -> vT transpose (u16 reads spread banks; b128 writes balanced)
  for (int i = tid; i < 256 * 6; i += 512) {
    int px = i & 255, j0 = (i >> 8) * 8;
    BF8 u;
#pragma unroll
    for (int e = 0; e < 8; ++e) u.h[e] = vl[(j0 + e) * 264 + px];
    *(uint4*)&vT[px * 56 + j0] = u.u;
  }
  __syncthreads();

  int w = tid >> 6, lane = tid & 63;
  int li = lane & 15, qd = lane >> 4;
  int mg = w & 3;          // M-tiles mg*3 .. mg*3+2  (48 o-rows)
  int nh = w >> 2;         // px half: nh*128 + nt*16 + li

  const __hip_bfloat16* ABb = AB + (size_t)b * 18432;

  floatx4 acc[3][8];
#pragma unroll
  for (int m = 0; m < 3; ++m)
#pragma unroll
    for (int nt = 0; nt < 8; ++nt) acc[m][nt] = (floatx4){0.f, 0.f, 0.f, 0.f};

#pragma unroll
  for (int s = 0; s < 3; ++s) {
    short8 a[3];
#pragma unroll
    for (int m = 0; m < 3; ++m)
      a[m] = *(const short8*)(ABb + (size_t)(((mg * 3 + m) * 3 + s) * 64 + lane) * 8);
    int t0 = s * 32 + qd * 8;
    int j0 = (t0 >= 48) ? t0 - 48 : t0;     // v row for this lane's k-slice
#pragma unroll
    for (int nt = 0; nt < 8; ++nt) {
      int n = nh * 128 + nt * 16 + li;
      short8 bv = *(const short8*)&vT[n * 56 + j0];
#pragma unroll
      for (int m = 0; m < 3; ++m)
        acc[m][nt] = __builtin_amdgcn_mfma_f32_16x16x32_bf16(a[m], bv, acc[m][nt], 0, 0, 0);
    }
  }

  // epilogue: 4 phases of 48 o-rows. D: row=qd*4+r, col=li.
#pragma unroll
  for (int ph = 0; ph < 4; ++ph) {
    __syncthreads();   // vT/vl reads done (ph0) / prev stores done
    if (mg == ph) {
#pragma unroll
      for (int m = 0; m < 3; ++m)
#pragma unroll
        for (int nt = 0; nt < 8; ++nt) {
          int col = nh * 128 + nt * 16 + li;
#pragma unroll
          for (int r = 0; r < 4; ++r)
            EPu[(m * 16 + qd * 4 + r) * 260 + col] = acc[m][nt][r];
        }
    }
    __syncthreads();
    for (int i = tid; i < 48 * 64; i += 512) {
      int row = i >> 6, c4 = (i & 63) * 4;
      float4 v4 = *(const float4*)&EPu[row * 260 + c4];
      *(float4*)&out[(size_t)(b * 192 + ph * 48 + row) * HW + n0 + c4] = v4;
    }
  }
}

// ============================================================================
// ws layout (float offsets):
//  0        qss   [4*192]      = 768
//  768      kss   [4*48]       = 192
//  960      attn  [4*8*24*24]  = 18432
//  19392    AB  bf16 [4*18432] (= 36864 float slots; was Mt)
//  56256    bias  [288]
//  56544    Ssum  [288]
//  56832    AF  bf16 [288*192]
//  111872   y   bf16 [4*288*HW]
//  37860608 kbuf bf16 [4*48*HW]
//  44152064 vbuf bf16 [4*48*HW]
// d_out scratch: qfull bf16 [4*192*HW] in lower half; dead before k_out writes.
// ============================================================================
extern "C" void kernel_launch(void* const* d_in, const int* in_sizes, int n_in,
                              void* d_out, int out_size, void* d_ws, size_t ws_size,
                              hipStream_t stream) {
  const float* x     = (const float*)d_in[0];
  const float* ln_w  = (const float*)d_in[1];
  const float* ln_b  = (const float*)d_in[2];
  const float* q_w   = (const float*)d_in[3];
  const float* q_dw  = (const float*)d_in[4];
  const float* kv_w  = (const float*)d_in[5];
  const float* kv_dw = (const float*)d_in[6];
  const float* projw = (const float*)d_in[7];
  const float* temp  = (const float*)d_in[8];
  float* out = (float*)d_out;
  float* wsf = (float*)d_ws;

  float* qss  = wsf;
  float* kss  = wsf + 768;
  float* attn = wsf + 960;
  __hip_bfloat16* AB = (__hip_bfloat16*)(wsf + 19392);
  float* bias = wsf + 56256;
  float* Ssum = wsf + 56544;
  __hip_bfloat16* AF = (__hip_bfloat16*)(wsf + 56832);
  __hip_bfloat16* y    = (__hip_bfloat16*)(wsf + 111872);
  __hip_bfloat16* kbuf = (__hip_bfloat16*)(wsf + 37860608);
  __hip_bfloat16* vbuf = (__hip_bfloat16*)(wsf + 44152064);
  __hip_bfloat16* qfull = (__hip_bfloat16*)d_out;   // scratch: overwritten by k_out

  hipMemsetAsync(wsf, 0, 19392 * sizeof(float), stream);  // qss+kss+attn accumulators
  hipLaunchKernelGGL(k_prep, dim3(33), dim3(256), 0, stream, q_w, kv_w, ln_w, ln_b, AF, bias, Ssum);
  hipLaunchKernelGGL(k_conv1r, dim3(NB * 256), dim3(512), 0, stream, x, AF, bias, Ssum, y);
  hipLaunchKernelGGL(k_dwkv, dim3(NB * 96 * 16), dim3(256), 0, stream, y, kv_dw, kbuf, vbuf, kss);
  hipLaunchKernelGGL(k_dwq,  dim3(NB * 192 * 16), dim3(256), 0, stream, y, q_dw, qfull, qss);
  hipLaunchKernelGGL(k_qk,   dim3(NB * 2 * 64), dim3(256), 0, stream, qfull, kbuf, attn);
  hipLaunchKernelGGL(k_attn_final, dim3(NB), dim3(256), 0, stream, attn, qss, kss, temp, projw, AB);
  hipLaunchKernelGGL(k_out,  dim3(NB * 256), dim3(512), 0, stream, vbuf, AB, out);
}